// Round 5
// baseline (158.248 us; speedup 1.0000x reference)
//
#include <hip/hip_runtime.h>
#include <hip/hip_bf16.h>
#include <math.h>

#define B_   128
#define LQ_  64
#define LD_  512
#define E_   300
#define K_   11
#define NCH  4      // d-chunks per batch
#define DCH  128    // LD_/NCH
#define BK   32     // e-slice per MFMA step
#define NT   10     // k-steps (covers 320, zero-padded past 300)
#define QSTR 328    // Q LDS row stride in bf16 elems
#define CSTR 130    // Cs LDS row stride in floats

typedef __bf16  bf16x8  __attribute__((ext_vector_type(8)));
typedef float   floatx4 __attribute__((ext_vector_type(4)));

__device__ __constant__ float MU_C[K_] =
    {1.0f, 0.9f, 0.7f, 0.5f, 0.3f, 0.1f, -0.1f, -0.3f, -0.5f, -0.7f, -0.9f};
__device__ __constant__ float NEGC_C[K_] =
    {-500000.0f, -50.0f, -50.0f, -50.0f, -50.0f, -50.0f,
     -50.0f, -50.0f, -50.0f, -50.0f, -50.0f};

__device__ __forceinline__ unsigned int pk2(float x, float y) {
    __hip_bfloat162 h = __float22bfloat162_rn(make_float2(x, y));
    union { __hip_bfloat162 h2; unsigned int u; } c;
    c.h2 = h;
    return c.u;
}

union __align__(16) ShBuf {
    unsigned short qs[LQ_ * QSTR];  // 41984 B (K-loop: Q bf16)
    float          cs[LQ_ * CSTR];  // 33280 B (epilogue: normalized sims)
};

// Fused GEMM + RBF pooling. Block = (batch, d-chunk of 128), 512 thr = 8 waves.
// D loads COALESCED (lane j -> row j>>3, bytes (j&7)*16: 128-B contiguous per
// row) then redistributed to MFMA B-fragment layout via wave-PRIVATE LDS tile
// (16-B-chunk XOR swizzle, no barriers). Q staged once flat-contiguous.
__global__ __launch_bounds__(512, 4) void knrm_main(
    const float* __restrict__ Q, const float* __restrict__ D,
    const float* __restrict__ mask_d, float* __restrict__ psum)
{
    const int b = blockIdx.y, ch = blockIdx.x, d0 = ch * DCH;
    const int tid  = threadIdx.x;
    const int lane = tid & 63;
    const int w    = tid >> 6;     // wave -> 16 d-rows
    const int quad = lane >> 4;
    const int l15  = lane & 15;
    const int jr   = lane >> 3;    // 0..7: row-sub for coalesced D loads
    const int jc   = lane & 7;     // 16-B chunk within the 128-B row slice

    __shared__ ShBuf sh;
    __shared__ __align__(16) float dtile[8][2][512]; // wave x dbuf x (16 rows * 32 f, swizzled)
    __shared__ float qssq[LQ_];
    __shared__ float qinv_s[LQ_];
    __shared__ float dinv_s[DCH];
    __shared__ float md_s[DCH];

    const float* dpB = D + ((size_t)b * LD_ + d0 + w * 16) * E_;

    // ---- coalesced D tile load: two dwordx4 per tile (rows jr and jr+8) ----
    auto loadD = [&](int t, float4 v[2]) {
        const int e = t * BK + jc * 4;
        if (e + 4 <= E_) {
            v[0] = *(const float4*)(dpB + (size_t)jr * E_ + e);
            v[1] = *(const float4*)(dpB + (size_t)(8 + jr) * E_ + e);
        } else {
            v[0] = make_float4(0.f, 0.f, 0.f, 0.f);
            v[1] = make_float4(0.f, 0.f, 0.f, 0.f);
        }
    };
    // swizzled store into this wave's private tile buffer + ssd accumulation
    auto writeD = [&](int t, const float4 v[2], float& sdl, float& sdh) {
        float* base = &dtile[w][t & 1][0];
        const int s = jc ^ jr;                 // chunk swizzle (rows differ by 8 -> same s)
        *(float4*)&base[jr * 32 + s * 4]       = v[0];
        *(float4*)&base[(8 + jr) * 32 + s * 4] = v[1];
        sdl += v[0].x * v[0].x + v[0].y * v[0].y + v[0].z * v[0].z + v[0].w * v[0].w;
        sdh += v[1].x * v[1].x + v[1].y * v[1].y + v[1].z * v[1].z + v[1].w * v[1].w;
    };
    // read back in MFMA B-fragment order: row l15, e = quad*8 .. +8
    auto readD = [&](int t, float dv[8]) {
        const float* base = &dtile[w][t & 1][0];
        const int s0 = (2 * quad) ^ (l15 & 7);
        const int s1 = s0 ^ 1;
        float4 a = *(const float4*)&base[l15 * 32 + s0 * 4];
        float4 c = *(const float4*)&base[l15 * 32 + s1 * 4];
        dv[0] = a.x; dv[1] = a.y; dv[2] = a.z; dv[3] = a.w;
        dv[4] = c.x; dv[5] = c.y; dv[6] = c.z; dv[7] = c.w;
    };

    float4 sl[2][2];
    loadD(0, sl[0]);           // tiles 0,1 in flight while Q stages
    loadD(1, sl[1]);

    if (tid < LQ_) qssq[tid] = 0.f;
    if (tid < DCH) md_s[tid] = mask_d[(size_t)b * LD_ + d0 + tid];
    __syncthreads();           // qssq zeroed

    // ---- Q staging: flat-contiguous fp32 reads of the 64x300 slice ----
    const float* qbase = Q + (size_t)b * LQ_ * E_;
#pragma unroll
    for (int k = 0; k < 10; ++k) {
        int g = tid + k * 512;             // float4 index, 4800 total
        if (g < 4800) {
            int row = (unsigned)g / 75u;
            int c4  = g - row * 75;
            float4 v = *(const float4*)(qbase + (size_t)g * 4);
            atomicAdd(&qssq[row], v.x * v.x + v.y * v.y + v.z * v.z + v.w * v.w);
            *(uint2*)&sh.qs[row * QSTR + c4 * 4] =
                make_uint2(pk2(v.x, v.y), pk2(v.z, v.w));
        }
    }
    if (tid < 320) {                       // zero-pad e in [300,320)
        int row = (unsigned)tid / 5u, slot = tid - row * 5;
        *(uint2*)&sh.qs[row * QSTR + 300 + slot * 4] = make_uint2(0u, 0u);
    }
    __syncthreads();                       // Qs + qssq complete
    if (tid < LQ_) qinv_s[tid] = 1.0f / fmaxf(sqrtf(qssq[tid]), 1e-12f);

    floatx4 acc[4];
    floatx4 zero4 = {0.f, 0.f, 0.f, 0.f};
#pragma unroll
    for (int mt = 0; mt < 4; ++mt) acc[mt] = zero4;

    float ssdl = 0.f, ssdh = 0.f;
    writeD(0, sl[0], ssdl, ssdh);

    // ---- barrier-free K-loop ----
#pragma unroll
    for (int t = 0; t < NT; ++t) {
        float dv[8];
        readD(t, dv);
        if (t + 1 < NT) writeD(t + 1, sl[(t + 1) & 1], ssdl, ssdh);
        if (t + 2 < NT) loadD(t + 2, sl[t & 1]);

        union { uint4 u; bf16x8 v; } bc;
        bc.u = make_uint4(pk2(dv[0], dv[1]), pk2(dv[2], dv[3]),
                          pk2(dv[4], dv[5]), pk2(dv[6], dv[7]));
        const int ebase = t * BK + quad * 8;
#pragma unroll
        for (int mt = 0; mt < 4; ++mt) {
            bf16x8 af = *(const bf16x8*)&sh.qs[(mt * 16 + l15) * QSTR + ebase];
            acc[mt] = __builtin_amdgcn_mfma_f32_16x16x32_bf16(af, bc.v, acc[mt], 0, 0, 0);
        }
    }

    // ---- d inv-norms: reduce over the 8 chunk-lanes, publish via LDS ----
    ssdl += __shfl_xor(ssdl, 1); ssdl += __shfl_xor(ssdl, 2); ssdl += __shfl_xor(ssdl, 4);
    ssdh += __shfl_xor(ssdh, 1); ssdh += __shfl_xor(ssdh, 2); ssdh += __shfl_xor(ssdh, 4);
    if (jc == 0) {
        dinv_s[w * 16 + jr]     = 1.0f / fmaxf(sqrtf(ssdl), 1e-12f);
        dinv_s[w * 16 + 8 + jr] = 1.0f / fmaxf(sqrtf(ssdh), 1e-12f);
    }
    // same-wave LDS write->read: compiler inserts lgkmcnt wait; no barrier needed
    const float dinv = dinv_s[w * 16 + l15];

    // ---- epilogue: normalized sims -> LDS (aliases Qs), repartition, pool ----
    __syncthreads();                // all Qs fragment reads done before aliasing
#pragma unroll
    for (int mt = 0; mt < 4; ++mt) {
#pragma unroll
        for (int r = 0; r < 4; ++r) {
            int q = mt * 16 + quad * 4 + r;
            sh.cs[q * CSTR + w * 16 + l15] = acc[mt][r] * qinv_s[q] * dinv;
        }
    }
    __syncthreads();

    const int pq = tid >> 3, pd = tid & 7;   // thread: q-row x 16-d slice
    float kacc[K_];
#pragma unroll
    for (int k = 0; k < K_; ++k) kacc[k] = 0.f;
#pragma unroll
    for (int j = 0; j < 16; ++j) {
        float s = sh.cs[pq * CSTR + pd * 16 + j];
        float m = md_s[pd * 16 + j];
#pragma unroll
        for (int k = 0; k < K_; ++k) {
            float df = s - MU_C[k];
            kacc[k] = fmaf(__expf(df * df * NEGC_C[k]), m, kacc[k]);
        }
    }
#pragma unroll
    for (int msk = 1; msk <= 4; msk <<= 1)
#pragma unroll
        for (int k = 0; k < K_; ++k) kacc[k] += __shfl_xor(kacc[k], msk);

    if (pd == 0) {
        const size_t base = (((size_t)b * NCH + ch) * LQ_ + pq) * K_;
#pragma unroll
        for (int k = 0; k < K_; ++k) psum[base + k] = kacc[k];
    }
}

// Combine chunk partials, log-pool, dense + tanh. One wave per batch.
__global__ __launch_bounds__(64) void knrm_final(
    const float* __restrict__ psum, const float* __restrict__ mask_q,
    const float* __restrict__ dw, const float* __restrict__ db,
    float* __restrict__ out)
{
    const int b = blockIdx.x;
    const int q = threadIdx.x;  // 0..63

    float t = 0.0f;
#pragma unroll
    for (int k = 0; k < K_; ++k) {
        float p = 0.0f;
#pragma unroll
        for (int c = 0; c < NCH; ++c)
            p += psum[(((size_t)b * NCH + c) * LQ_ + q) * K_ + k];
        p = fmaxf(p, 1e-10f);
        t += logf(p) * dw[k];
    }
    t *= 0.01f * mask_q[(size_t)b * LQ_ + q];

#pragma unroll
    for (int m = 32; m >= 1; m >>= 1) t += __shfl_xor(t, m);
    if (q == 0) out[b] = tanhf(t + db[0]);
}

extern "C" void kernel_launch(void* const* d_in, const int* in_sizes, int n_in,
                              void* d_out, int out_size, void* d_ws, size_t ws_size,
                              hipStream_t stream) {
    const float* Q   = (const float*)d_in[0];  // [B, LQ, E]
    const float* D   = (const float*)d_in[1];  // [B, LD, E]
    const float* mq  = (const float*)d_in[2];  // [B, LQ]
    const float* md  = (const float*)d_in[3];  // [B, LD]
    const float* dw  = (const float*)d_in[4];  // [1, K]
    const float* db  = (const float*)d_in[5];  // [1]
    float* out  = (float*)d_out;               // [B, 1]
    float* psum = (float*)d_ws;                // [B][NCH][LQ][K] = 1.4 MB

    dim3 grid(NCH, B_);
    knrm_main<<<grid, 512, 0, stream>>>(Q, D, md, psum);
    knrm_final<<<B_, 64, 0, stream>>>(psum, mq, dw, db, out);
}